// Round 13
// baseline (1436.212 us; speedup 1.0000x reference)
//
#include <hip/hip_runtime.h>

#define NNODES 100000
#define NEDGES 1600000
#define NGRAPHS 2048
#define BN_EPS 1e-5f

typedef __attribute__((ext_vector_type(8))) short bf16x8;
typedef __attribute__((ext_vector_type(4))) float f32x4;

// RNE float -> bf16 (as short bits)
__device__ __forceinline__ short f2bf(float x) {
    unsigned u = __float_as_uint(x);
    unsigned r = u + 0x7FFF + ((u >> 16) & 1);
    return (short)(r >> 16);
}
__device__ __forceinline__ float bf2f(short h) {
    return __uint_as_float(((unsigned)(unsigned short)h) << 16);
}

// ---------------- CSR build ----------------
__global__ __launch_bounds__(256) void deg_kernel(const int* __restrict__ dstA,
                                                  int* __restrict__ deg) {
    int e = blockIdx.x * 256 + threadIdx.x;
    if (e < NEDGES) atomicAdd(&deg[dstA[e]], 1);
}

__global__ __launch_bounds__(256) void scan1_kernel(const int* __restrict__ deg,
                                                    int* __restrict__ partials) {
    int b = blockIdx.x;
    int i = b * 256 + threadIdx.x;
    int v = (i < NNODES) ? deg[i] : 0;
    __shared__ int wsum[4];
#pragma unroll
    for (int off = 32; off; off >>= 1) v += __shfl_down(v, off);
    if ((threadIdx.x & 63) == 0) wsum[threadIdx.x >> 6] = v;
    __syncthreads();
    if (threadIdx.x == 0) partials[b] = wsum[0] + wsum[1] + wsum[2] + wsum[3];
}

__global__ __launch_bounds__(512) void scan2_kernel(int* __restrict__ partials, int nb) {
    __shared__ int s[512];
    int t = threadIdx.x;
    int v = (t < nb) ? partials[t] : 0;
    s[t] = v;
    __syncthreads();
    for (int off = 1; off < 512; off <<= 1) {
        int u = (t >= off) ? s[t - off] : 0;
        __syncthreads();
        s[t] += u;
        __syncthreads();
    }
    if (t < nb) partials[t] = s[t] - v;  // exclusive
}

__global__ __launch_bounds__(256) void scan3_kernel(const int* __restrict__ deg,
                                                    const int* __restrict__ partials,
                                                    int* __restrict__ rowptr,
                                                    int* __restrict__ cursor,
                                                    const int* __restrict__ batch,
                                                    int* __restrict__ gstart) {
    int b = blockIdx.x;
    int t = threadIdx.x;
    int i = b * 256 + t;
    __shared__ int s[256];
    int v = (i < NNODES) ? deg[i] : 0;
    s[t] = v;
    __syncthreads();
    for (int off = 1; off < 256; off <<= 1) {
        int u = (t >= off) ? s[t - off] : 0;
        __syncthreads();
        s[t] += u;
        __syncthreads();
    }
    if (i < NNODES) {
        int ex = partials[b] + s[t] - v;
        rowptr[i] = ex;
        cursor[i] = ex;
        int bb = batch[i];
        int bp = (i == 0) ? -1 : batch[i - 1];
        for (int g = bp + 1; g <= bb; ++g) gstart[g] = i;
        if (i == NNODES - 1)
            for (int g = bb + 1; g <= NGRAPHS; ++g) gstart[g] = NNODES;
    }
    if (b == 0 && t == 0) rowptr[NNODES] = NEDGES;
}

__global__ __launch_bounds__(256) void fill_kernel(const int* __restrict__ srcA,
                                                   const int* __restrict__ dstA,
                                                   int* __restrict__ cursor,
                                                   int* __restrict__ adj) {
    int e = blockIdx.x * 256 + threadIdx.x;
    if (e < NEDGES) {
        int d = dstA[e];
        int loc = atomicAdd(&cursor[d], 1);
        adj[loc] = srcA[e];
    }
}

// ------- gather aggregation: agg[n] = x[n] + sum_{s in adj[n]} x[s] (+bias) -------
// FS: fuse per-column sum/sumsq into stats (grid must cover exactly NNODES*PE threads,
// which holds for DIM=128: 100000*32/256 = 12500 blocks exact — no early-return stragglers
// at the barriers).
template <int DIM, int CHUNK, int OSTRIDE, bool FS>
__global__ __launch_bounds__(256) void gather_kernel(const float* __restrict__ x,
                                                     const int* __restrict__ rowptr,
                                                     const int* __restrict__ adj,
                                                     float* __restrict__ agg,
                                                     const float* __restrict__ bias,
                                                     float* __restrict__ stats) {
    constexpr int PE = DIM / CHUNK;
    __shared__ float sstat[256];
    int gid = blockIdx.x * 256 + threadIdx.x;
    if (gid >= NNODES * PE) return;
    int node = gid / PE;
    int c = gid - node * PE;
    const int beg = rowptr[node];
    const int end = rowptr[node + 1];
    if (CHUNK == 4) {
        if (FS) {
            sstat[threadIdx.x] = 0.f;
            __syncthreads();
        }
        const float4* xp = (const float4*)x;
        float4 acc = xp[(size_t)node * PE + c];
        for (int i = beg; i < end; ++i) {
            int s = adj[i];
            float4 v = xp[(size_t)s * PE + c];
            acc.x += v.x;
            acc.y += v.y;
            acc.z += v.z;
            acc.w += v.w;
        }
        if (bias) {
            float4 b = *(const float4*)&bias[c * 4];
            acc.x += b.x; acc.y += b.y; acc.z += b.z; acc.w += b.w;
        }
        *(float4*)&agg[(size_t)node * OSTRIDE + c * 4] = acc;
        if (FS) {
            atomicAdd(&sstat[c * 4 + 0], acc.x);
            atomicAdd(&sstat[c * 4 + 1], acc.y);
            atomicAdd(&sstat[c * 4 + 2], acc.z);
            atomicAdd(&sstat[c * 4 + 3], acc.w);
            atomicAdd(&sstat[128 + c * 4 + 0], acc.x * acc.x);
            atomicAdd(&sstat[128 + c * 4 + 1], acc.y * acc.y);
            atomicAdd(&sstat[128 + c * 4 + 2], acc.z * acc.z);
            atomicAdd(&sstat[128 + c * 4 + 3], acc.w * acc.w);
            __syncthreads();
            if (threadIdx.x < 128) {
                atomicAdd(&stats[threadIdx.x], sstat[threadIdx.x]);
                atomicAdd(&stats[256 + threadIdx.x], sstat[128 + threadIdx.x]);
            }
        }
    } else {
        const float2* xp = (const float2*)x;
        float2 acc = xp[(size_t)node * PE + c];
        for (int i = beg; i < end; ++i) {
            int s = adj[i];
            float2 v = xp[(size_t)s * PE + c];
            acc.x += v.x;
            acc.y += v.y;
        }
        *(float2*)&agg[(size_t)node * OSTRIDE + c * 2] = acc;
    }
}

// reads sums (sum@c, sumsq@256+c), writes scale@c / shift@256+c, then re-zeroes sums.
__global__ void bnfinal_kernel(float* __restrict__ sums, const float* __restrict__ gamma,
                               const float* __restrict__ beta, float* __restrict__ scsh, int N,
                               float invM) {
    int c = threadIdx.x;  // 256 threads always
    if (c < N) {
        float mean = sums[c] * invM;
        float var = sums[256 + c] * invM - mean * mean;
        float sc = gamma[c] * rsqrtf(var + BN_EPS);
        scsh[c] = sc;
        scsh[256 + c] = beta[c] - mean * sc;
    }
    sums[c] = 0.f;
    sums[256 + c] = 0.f;
}

// ---- W pre-pass: decompose W (Kw x N fp32) into hi/lo bf16 B-fragments ----
// B-frag layout (mfma_f32_16x16x32_bf16): lane holds n=lane&15, k=(lane>>4)*8+j.
// Buffer index: ((nt*KT + kt)*64 + lane)*8 + j.
__global__ __launch_bounds__(256) void wprep_kernel(const float* __restrict__ W, int Kw, int N,
                                                    int KT, short* __restrict__ whi,
                                                    short* __restrict__ wlo) {
    int idx = blockIdx.x * 256 + threadIdx.x;
    int total = (N >> 4) * KT * 512;
    if (idx >= total) return;
    int j = idx & 7;
    int lane = (idx >> 3) & 63;
    int t = idx >> 9;  // nt*KT + kt
    int kt = t % KT;
    int nt = t / KT;
    int k = kt * 32 + ((lane >> 4) << 3) + j;
    int n = (nt << 4) + (lane & 15);
    float w = (k < Kw) ? W[(size_t)k * N + n] : 0.f;
    short hi = f2bf(w);
    short lo = f2bf(w - bf2f(hi));
    whi[idx] = hi;
    wlo[idx] = lo;
}

// ---------------- split-bf16 MFMA GEMM: C = op(A) @ W + bias ----------------
// LDS-free. Block = 4 waves; BM=64 (16 rows/wave); NT N-tiles per block.
// blockIdx.y = N-group (whi/wlo, bias, C column offsets). SPLITK: blockIdx.z picks a
// KT-chunk of size ktc, C offset by z*M*N (partials; bias usually nullptr).
template <int NT, bool BNRELU_A, bool RELU_OUT, bool FUSE_STATS, bool SPLITK>
__global__ __launch_bounds__(256) void gemm_mfma_kernel(
    const float* __restrict__ A, const short* __restrict__ whi, const short* __restrict__ wlo,
    const float* __restrict__ bias, const float* __restrict__ scsh, float* __restrict__ C,
    float* __restrict__ stats, int M, int Kst, int KT, int N, int ktc) {
    __shared__ float sstat[512];
    const int tid = threadIdx.x;
    const int wave = tid >> 6;
    const int lane = tid & 63;
    const int quad = lane >> 4;
    const int l16 = lane & 15;
    const int mrow = blockIdx.x * 64 + wave * 16 + l16;
    const int ngrp = blockIdx.y * NT * 16;
    const size_t wgrp = (size_t)blockIdx.y * NT * KT * 512;
    const int ktbeg = SPLITK ? blockIdx.z * ktc : 0;
    const int ktend = SPLITK ? ktbeg + ktc : KT;
    float* Cb = SPLITK ? C + (size_t)blockIdx.z * M * N : C;

    if (FUSE_STATS) {
        sstat[tid] = 0.f;
        sstat[tid + 256] = 0.f;
        __syncthreads();
    }

    f32x4 acc[NT] = {};

    for (int kt = ktbeg; kt < ktend; ++kt) {
        const int kq = kt * 32 + quad * 8;
        const float* ap = A + (size_t)mrow * Kst + kq;
        float4 x0 = *(const float4*)ap;
        float4 x1 = *(const float4*)(ap + 4);
        float a8[8] = {x0.x, x0.y, x0.z, x0.w, x1.x, x1.y, x1.z, x1.w};
        if (BNRELU_A) {
            float4 sc0 = *(const float4*)&scsh[kq];
            float4 sc1 = *(const float4*)&scsh[kq + 4];
            float4 sh0 = *(const float4*)&scsh[256 + kq];
            float4 sh1 = *(const float4*)&scsh[256 + kq + 4];
            float sc[8] = {sc0.x, sc0.y, sc0.z, sc0.w, sc1.x, sc1.y, sc1.z, sc1.w};
            float sh[8] = {sh0.x, sh0.y, sh0.z, sh0.w, sh1.x, sh1.y, sh1.z, sh1.w};
#pragma unroll
            for (int i = 0; i < 8; ++i) a8[i] = fmaxf(a8[i] * sc[i] + sh[i], 0.f);
        }
        bf16x8 ahi, alo;
#pragma unroll
        for (int i = 0; i < 8; ++i) {
            short h = f2bf(a8[i]);
            ahi[i] = h;
            alo[i] = f2bf(a8[i] - bf2f(h));
        }
#pragma unroll
        for (int nt = 0; nt < NT; ++nt) {
            const size_t boff = wgrp + (((size_t)nt * KT + kt) << 9) + (lane << 3);
            bf16x8 bh = *(const bf16x8*)(whi + boff);
            bf16x8 bl = *(const bf16x8*)(wlo + boff);
            acc[nt] = __builtin_amdgcn_mfma_f32_16x16x32_bf16(ahi, bh, acc[nt], 0, 0, 0);
            acc[nt] = __builtin_amdgcn_mfma_f32_16x16x32_bf16(alo, bh, acc[nt], 0, 0, 0);
            acc[nt] = __builtin_amdgcn_mfma_f32_16x16x32_bf16(ahi, bl, acc[nt], 0, 0, 0);
            acc[nt] = __builtin_amdgcn_mfma_f32_16x16x32_bf16(alo, bl, acc[nt], 0, 0, 0);
        }
    }

    // Epilogue. C/D frag: col = l16 (+16*nt), row = quad*4 + reg (m89-verified).
    const int mbase = blockIdx.x * 64 + wave * 16 + quad * 4;
#pragma unroll
    for (int nt = 0; nt < NT; ++nt) {
        int gn = ngrp + nt * 16 + l16;
        float bv = bias ? bias[gn] : 0.f;
        float s = 0.f, s2 = 0.f;
#pragma unroll
        for (int r = 0; r < 4; ++r) {
            int gm = mbase + r;
            float v = acc[nt][r] + bv;
            if (RELU_OUT) v = fmaxf(v, 0.f);
            if (gm < M) {
                Cb[(size_t)gm * N + gn] = v;
                if (FUSE_STATS) {
                    s += v;
                    s2 += v * v;
                }
            }
        }
        if (FUSE_STATS) {
            s += __shfl_xor(s, 16);
            s += __shfl_xor(s, 32);
            s2 += __shfl_xor(s2, 16);
            s2 += __shfl_xor(s2, 32);
            if (quad == 0) {
                atomicAdd(&sstat[gn], s);
                atomicAdd(&sstat[256 + gn], s2);
            }
        }
    }
    if (FUSE_STATS) {
        __syncthreads();
        if (tid < N) {
            atomicAdd(&stats[tid], sstat[tid]);
            atomicAdd(&stats[256 + tid], sstat[256 + tid]);
        }
    }
}

// ---- reduce 8 split-K partials + bias -> out (fc1: M=2048,N=128) ----
__global__ __launch_bounds__(256) void splitk_reduce_kernel(const float* __restrict__ part,
                                                            const float* __restrict__ bias,
                                                            float* __restrict__ out) {
    const int i4 = blockIdx.x * 256 + threadIdx.x;
    const int TOT4 = NGRAPHS * 128 / 4;  // 65536
    if (i4 >= TOT4) return;
    const float4* p = (const float4*)part;
    float4 acc = make_float4(0.f, 0.f, 0.f, 0.f);
#pragma unroll
    for (int c = 0; c < 8; ++c) {
        float4 v = p[(size_t)c * TOT4 + i4];
        acc.x += v.x; acc.y += v.y; acc.z += v.z; acc.w += v.w;
    }
    float4 b = ((const float4*)bias)[i4 & 31];
    acc.x += b.x; acc.y += b.y; acc.z += b.z; acc.w += b.w;
    ((float4*)out)[i4] = acc;
}

// ---- segmented pool over sorted batch ----
__global__ __launch_bounds__(128) void pool_seg_kernel(const float* __restrict__ h,
                                                       const int* __restrict__ gstart,
                                                       float* __restrict__ g) {
    int gr = blockIdx.x;
    int t = threadIdx.x;
    int beg = gstart[gr];
    int end = gstart[gr + 1];
    float acc = 0.f;
    for (int r = beg; r < end; ++r) acc += h[(size_t)r * 128 + t];
    g[(size_t)gr * 128 + t] = acc;
}

extern "C" void kernel_launch(void* const* d_in, const int* in_sizes, int n_in, void* d_out,
                              int out_size, void* d_ws, size_t ws_size, hipStream_t stream) {
    const float* x = (const float*)d_in[0];
    const int* ei = (const int*)d_in[1];
    const int* batch = (const int*)d_in[2];
    const int* srcA = ei;
    const int* dstA = ei + NEDGES;

    const float* g0_w1 = (const float*)d_in[3];
    const float* g0_b1 = (const float*)d_in[4];
    const float* g0_ga = (const float*)d_in[5];
    const float* g0_be = (const float*)d_in[6];
    const float* g0_w2 = (const float*)d_in[7];
    const float* g0_b2 = (const float*)d_in[8];
    const float* g1_w1 = (const float*)d_in[9];
    const float* g1_b1 = (const float*)d_in[10];
    const float* g1_ga = (const float*)d_in[11];
    const float* g1_be = (const float*)d_in[12];
    const float* g1_w2 = (const float*)d_in[13];
    const float* g1_b2 = (const float*)d_in[14];
    const float* g2_w1 = (const float*)d_in[15];
    const float* g2_b1 = (const float*)d_in[16];
    const float* g2_ga = (const float*)d_in[17];
    const float* g2_be = (const float*)d_in[18];
    const float* g2_w2 = (const float*)d_in[19];
    const float* g2_b2 = (const float*)d_in[20];
    const float* fc0_w = (const float*)d_in[21];
    const float* fc0_b = (const float*)d_in[22];
    const float* fc1_w = (const float*)d_in[23];
    const float* fc1_b = (const float*)d_in[24];

    // --- workspace layout (~228 MB) ---
    float* ws = (float*)d_ws;
    const size_t BUF = (size_t)NNODES * 256;
    float* R0 = ws;
    float* R1 = R0 + BUF;  // also fc1 split-K partial buffer (8*2048*128 = 2.1M floats)
    float* stats = R1 + BUF;                         // 512
    float* scsh = stats + 512;                       // 512
    float* g = scsh + 512;                           // 2048*128 pooled
    float* gh = g + (size_t)NGRAPHS * 128;           // 2048*1024 fc hidden
    int* deg = (int*)(gh + (size_t)NGRAPHS * 1024);  // NNODES
    int* rowptr = deg + NNODES;                      // NNODES+1
    int* cursor = rowptr + NNODES + 4;               // NNODES
    int* adj = cursor + NNODES;                      // NEDGES
    int* partials = adj + NEDGES;                    // 391
    int* gstart = partials + 512;                    // NGRAPHS+1
    // W-fragment slots: 6 GIN (65536 hi + 65536 lo) + fc0/fc1 (131072 hi + 131072 lo each)
    short* wf = (short*)(gstart + 2052);
    short* whi[8];
    short* wlo[8];
    for (int i = 0; i < 6; ++i) {
        whi[i] = wf + (size_t)i * 131072;
        wlo[i] = whi[i] + 65536;
    }
    whi[6] = wf + 6 * 131072;
    wlo[6] = whi[6] + 131072;
    whi[7] = whi[6] + 262144;
    wlo[7] = whi[7] + 131072;

    const int GB = (NNODES + 63) / 64;    // 1563 mfma-GEMM row-blocks
    const int NB = (NNODES + 255) / 256;  // 391 scan blocks

    // --- build CSR + graph bounds once ---
    hipMemsetAsync(deg, 0, NNODES * sizeof(int), stream);
    hipMemsetAsync(stats, 0, 512 * sizeof(float), stream);  // bnfinal re-zeroes thereafter
    deg_kernel<<<(NEDGES + 255) / 256, 256, 0, stream>>>(dstA, deg);
    scan1_kernel<<<NB, 256, 0, stream>>>(deg, partials);
    scan2_kernel<<<1, 512, 0, stream>>>(partials, NB);
    scan3_kernel<<<NB, 256, 0, stream>>>(deg, partials, rowptr, cursor, batch, gstart);
    fill_kernel<<<(NEDGES + 255) / 256, 256, 0, stream>>>(srcA, dstA, cursor, adj);

    // --- W-fragment pre-passes ---
    wprep_kernel<<<(8 * 3 * 512 + 255) / 256, 256, 0, stream>>>(g0_w1, 66, 128, 3, whi[0], wlo[0]);
    wprep_kernel<<<(8 * 4 * 512 + 255) / 256, 256, 0, stream>>>(g0_w2, 128, 128, 4, whi[1], wlo[1]);
    wprep_kernel<<<(16 * 4 * 512 + 255) / 256, 256, 0, stream>>>(g1_w1, 128, 256, 4, whi[2], wlo[2]);
    wprep_kernel<<<(16 * 8 * 512 + 255) / 256, 256, 0, stream>>>(g1_w2, 256, 256, 8, whi[3], wlo[3]);
    wprep_kernel<<<(8 * 8 * 512 + 255) / 256, 256, 0, stream>>>(g2_w1, 256, 128, 8, whi[4], wlo[4]);
    wprep_kernel<<<(8 * 4 * 512 + 255) / 256, 256, 0, stream>>>(g2_w2, 128, 128, 4, whi[5], wlo[5]);
    wprep_kernel<<<(64 * 4 * 512 + 255) / 256, 256, 0, stream>>>(fc0_w, 128, 1024, 4, whi[6], wlo[6]);
    wprep_kernel<<<(8 * 32 * 512 + 255) / 256, 256, 0, stream>>>(fc1_w, 1024, 128, 32, whi[7], wlo[7]);

    // ================= Layer 0 (66 -> 128 -> 128) =================
    gather_kernel<66, 2, 68, false><<<(NNODES * 33 + 255) / 256, 256, 0, stream>>>(
        x, rowptr, adj, R0, nullptr, nullptr);
    gemm_mfma_kernel<8, false, false, true, false><<<GB, 256, 0, stream>>>(
        R0, whi[0], wlo[0], g0_b1, nullptr, R1, stats, NNODES, 68, 3, 128, 0);
    bnfinal_kernel<<<1, 256, 0, stream>>>(stats, g0_ga, g0_be, scsh, 128, 1.0f / NNODES);
    gemm_mfma_kernel<8, true, true, false, false><<<GB, 256, 0, stream>>>(
        R1, whi[1], wlo[1], g0_b2, scsh, R0, nullptr, NNODES, 128, 4, 128, 0);

    // ================= Layer 1 (128 -> 256 -> 256) =================
    gather_kernel<128, 4, 128, false><<<(NNODES * 32 + 255) / 256, 256, 0, stream>>>(
        R0, rowptr, adj, R1, nullptr, nullptr);
    gemm_mfma_kernel<16, false, false, true, false><<<GB, 256, 0, stream>>>(
        R1, whi[2], wlo[2], g1_b1, nullptr, R0, stats, NNODES, 128, 4, 256, 0);
    bnfinal_kernel<<<1, 256, 0, stream>>>(stats, g1_ga, g1_be, scsh, 256, 1.0f / NNODES);
    gemm_mfma_kernel<16, true, true, false, false><<<GB, 256, 0, stream>>>(
        R0, whi[3], wlo[3], g1_b2, scsh, R1, nullptr, NNODES, 256, 8, 256, 0);

    // ================= Layer 2 (256 -> 128 -> 128), REORDERED =================
    gemm_mfma_kernel<8, false, false, false, false><<<GB, 256, 0, stream>>>(
        R1, whi[4], wlo[4], nullptr, nullptr, R0, nullptr, NNODES, 256, 8, 128, 0);
    // gather at 128 with fused BN stats (saves the separate bnstats pass)
    gather_kernel<128, 4, 128, true><<<(NNODES * 32 + 255) / 256, 256, 0, stream>>>(
        R0, rowptr, adj, R1, g2_b1, stats);
    bnfinal_kernel<<<1, 256, 0, stream>>>(stats, g2_ga, g2_be, scsh, 128, 1.0f / NNODES);
    gemm_mfma_kernel<8, true, true, false, false><<<GB, 256, 0, stream>>>(
        R1, whi[5], wlo[5], g2_b2, scsh, R0, nullptr, NNODES, 128, 4, 128, 0);

    // ================= pool + FC head (all MFMA) =================
    pool_seg_kernel<<<NGRAPHS, 128, 0, stream>>>(R0, gstart, g);

    // fc0: relu(g @ fc0_w + fc0_b) -> gh. grid (2048/64, 1024/(8*16)) = (32, 8).
    gemm_mfma_kernel<8, false, true, false, false><<<dim3(NGRAPHS / 64, 8), 256, 0, stream>>>(
        g, whi[6], wlo[6], fc0_b, nullptr, gh, nullptr, NGRAPHS, 128, 4, 1024, 0);
    // fc1 split-K: 8 chunks of KT=4 -> partials in R1 (dead here), then reduce+bias.
    gemm_mfma_kernel<8, false, false, false, true><<<dim3(NGRAPHS / 64, 1, 8), 256, 0, stream>>>(
        gh, whi[7], wlo[7], nullptr, nullptr, R1, nullptr, NGRAPHS, 1024, 32, 128, 4);
    splitk_reduce_kernel<<<(NGRAPHS * 128 / 4 + 255) / 256, 256, 0, stream>>>(R1, fc1_b,
                                                                              (float*)d_out);
}

// Round 14
// 1242.668 us; speedup vs baseline: 1.1557x; 1.1557x over previous
//
#include <hip/hip_runtime.h>

#define NNODES 100000
#define NEDGES 1600000
#define NGRAPHS 2048
#define BN_EPS 1e-5f

typedef __attribute__((ext_vector_type(8))) short bf16x8;
typedef __attribute__((ext_vector_type(4))) float f32x4;

// RNE float -> bf16 (as short bits)
__device__ __forceinline__ short f2bf(float x) {
    unsigned u = __float_as_uint(x);
    unsigned r = u + 0x7FFF + ((u >> 16) & 1);
    return (short)(r >> 16);
}
__device__ __forceinline__ float bf2f(short h) {
    return __uint_as_float(((unsigned)(unsigned short)h) << 16);
}

// ---------------- CSR build ----------------
__global__ __launch_bounds__(256) void deg_kernel(const int* __restrict__ dstA,
                                                  int* __restrict__ deg) {
    int e = blockIdx.x * 256 + threadIdx.x;
    if (e < NEDGES) atomicAdd(&deg[dstA[e]], 1);
}

__global__ __launch_bounds__(256) void scan1_kernel(const int* __restrict__ deg,
                                                    int* __restrict__ partials) {
    int b = blockIdx.x;
    int i = b * 256 + threadIdx.x;
    int v = (i < NNODES) ? deg[i] : 0;
    __shared__ int wsum[4];
#pragma unroll
    for (int off = 32; off; off >>= 1) v += __shfl_down(v, off);
    if ((threadIdx.x & 63) == 0) wsum[threadIdx.x >> 6] = v;
    __syncthreads();
    if (threadIdx.x == 0) partials[b] = wsum[0] + wsum[1] + wsum[2] + wsum[3];
}

__global__ __launch_bounds__(512) void scan2_kernel(int* __restrict__ partials, int nb) {
    __shared__ int s[512];
    int t = threadIdx.x;
    int v = (t < nb) ? partials[t] : 0;
    s[t] = v;
    __syncthreads();
    for (int off = 1; off < 512; off <<= 1) {
        int u = (t >= off) ? s[t - off] : 0;
        __syncthreads();
        s[t] += u;
        __syncthreads();
    }
    if (t < nb) partials[t] = s[t] - v;  // exclusive
}

__global__ __launch_bounds__(256) void scan3_kernel(const int* __restrict__ deg,
                                                    const int* __restrict__ partials,
                                                    int* __restrict__ rowptr,
                                                    int* __restrict__ cursor,
                                                    const int* __restrict__ batch,
                                                    int* __restrict__ gstart) {
    int b = blockIdx.x;
    int t = threadIdx.x;
    int i = b * 256 + t;
    __shared__ int s[256];
    int v = (i < NNODES) ? deg[i] : 0;
    s[t] = v;
    __syncthreads();
    for (int off = 1; off < 256; off <<= 1) {
        int u = (t >= off) ? s[t - off] : 0;
        __syncthreads();
        s[t] += u;
        __syncthreads();
    }
    if (i < NNODES) {
        int ex = partials[b] + s[t] - v;
        rowptr[i] = ex;
        cursor[i] = ex;
        int bb = batch[i];
        int bp = (i == 0) ? -1 : batch[i - 1];
        for (int g = bp + 1; g <= bb; ++g) gstart[g] = i;
        if (i == NNODES - 1)
            for (int g = bb + 1; g <= NGRAPHS; ++g) gstart[g] = NNODES;
    }
    if (b == 0 && t == 0) rowptr[NNODES] = NEDGES;
}

__global__ __launch_bounds__(256) void fill_kernel(const int* __restrict__ srcA,
                                                   const int* __restrict__ dstA,
                                                   int* __restrict__ cursor,
                                                   int* __restrict__ adj) {
    int e = blockIdx.x * 256 + threadIdx.x;
    if (e < NEDGES) {
        int d = dstA[e];
        int loc = atomicAdd(&cursor[d], 1);
        adj[loc] = srcA[e];
    }
}

// ------- gather aggregation: agg[n] = x[n] + sum_{s in adj[n]} x[s] (+bias) -------
// R13 post-mortem: fusing BN stats here (12500 blocks x 256 global atomics on one 2KB
// region) serialized the kernel tail: 127 -> 405us. Stats stay in the 128-block
// standalone bnstats kernel.
template <int DIM, int CHUNK, int OSTRIDE>
__global__ __launch_bounds__(256) void gather_kernel(const float* __restrict__ x,
                                                     const int* __restrict__ rowptr,
                                                     const int* __restrict__ adj,
                                                     float* __restrict__ agg,
                                                     const float* __restrict__ bias) {
    constexpr int PE = DIM / CHUNK;
    int gid = blockIdx.x * 256 + threadIdx.x;
    if (gid >= NNODES * PE) return;
    int node = gid / PE;
    int c = gid - node * PE;
    const int beg = rowptr[node];
    const int end = rowptr[node + 1];
    if (CHUNK == 4) {
        const float4* xp = (const float4*)x;
        float4 acc = xp[(size_t)node * PE + c];
        for (int i = beg; i < end; ++i) {
            int s = adj[i];
            float4 v = xp[(size_t)s * PE + c];
            acc.x += v.x;
            acc.y += v.y;
            acc.z += v.z;
            acc.w += v.w;
        }
        if (bias) {
            float4 b = *(const float4*)&bias[c * 4];
            acc.x += b.x; acc.y += b.y; acc.z += b.z; acc.w += b.w;
        }
        *(float4*)&agg[(size_t)node * OSTRIDE + c * 4] = acc;
    } else {
        const float2* xp = (const float2*)x;
        float2 acc = xp[(size_t)node * PE + c];
        for (int i = beg; i < end; ++i) {
            int s = adj[i];
            float2 v = xp[(size_t)s * PE + c];
            acc.x += v.x;
            acc.y += v.y;
        }
        *(float2*)&agg[(size_t)node * OSTRIDE + c * 2] = acc;
    }
}

// ---------------- BN stats (standalone, used once for L2) ----------------
template <int N>
__global__ __launch_bounds__(256) void bnstats_kernel(const float* __restrict__ h,
                                                      float* __restrict__ sums) {
    constexpr int SHIFT = (N == 128) ? 7 : 8;
    int t = blockIdx.x * 256 + threadIdx.x;
    int col = t & (N - 1);
    int slice = t >> SHIFT;
    float s = 0.f, s2 = 0.f;
    for (int r = slice; r < NNODES; r += 256) {
        float v = h[(size_t)r * N + col];
        s += v;
        s2 += v * v;
    }
    atomicAdd(&sums[col], s);
    atomicAdd(&sums[256 + col], s2);
}

// reads sums (sum@c, sumsq@256+c), writes scale@c / shift@256+c, then re-zeroes sums.
__global__ void bnfinal_kernel(float* __restrict__ sums, const float* __restrict__ gamma,
                               const float* __restrict__ beta, float* __restrict__ scsh, int N,
                               float invM) {
    int c = threadIdx.x;  // 256 threads always
    if (c < N) {
        float mean = sums[c] * invM;
        float var = sums[256 + c] * invM - mean * mean;
        float sc = gamma[c] * rsqrtf(var + BN_EPS);
        scsh[c] = sc;
        scsh[256 + c] = beta[c] - mean * sc;
    }
    sums[c] = 0.f;
    sums[256 + c] = 0.f;
}

// ---- W pre-pass: decompose W (Kw x N fp32) into hi/lo bf16 B-fragments ----
// B-frag layout (mfma_f32_16x16x32_bf16): lane holds n=lane&15, k=(lane>>4)*8+j.
// Buffer index: ((nt*KT + kt)*64 + lane)*8 + j.
__global__ __launch_bounds__(256) void wprep_kernel(const float* __restrict__ W, int Kw, int N,
                                                    int KT, short* __restrict__ whi,
                                                    short* __restrict__ wlo) {
    int idx = blockIdx.x * 256 + threadIdx.x;
    int total = (N >> 4) * KT * 512;
    if (idx >= total) return;
    int j = idx & 7;
    int lane = (idx >> 3) & 63;
    int t = idx >> 9;  // nt*KT + kt
    int kt = t % KT;
    int nt = t / KT;
    int k = kt * 32 + ((lane >> 4) << 3) + j;
    int n = (nt << 4) + (lane & 15);
    float w = (k < Kw) ? W[(size_t)k * N + n] : 0.f;
    short hi = f2bf(w);
    short lo = f2bf(w - bf2f(hi));
    whi[idx] = hi;
    wlo[idx] = lo;
}

// ---------------- split-bf16 MFMA GEMM: C = op(A) @ W + bias ----------------
// LDS-free. Block = 4 waves; BM=64 (16 rows/wave); NT N-tiles per block.
// blockIdx.y = N-group. SPLITK: blockIdx.z picks a KT-chunk of size ktc, C offset z*M*N.
template <int NT, bool BNRELU_A, bool RELU_OUT, bool FUSE_STATS, bool SPLITK>
__global__ __launch_bounds__(256) void gemm_mfma_kernel(
    const float* __restrict__ A, const short* __restrict__ whi, const short* __restrict__ wlo,
    const float* __restrict__ bias, const float* __restrict__ scsh, float* __restrict__ C,
    float* __restrict__ stats, int M, int Kst, int KT, int N, int ktc) {
    __shared__ float sstat[512];
    const int tid = threadIdx.x;
    const int wave = tid >> 6;
    const int lane = tid & 63;
    const int quad = lane >> 4;
    const int l16 = lane & 15;
    const int mrow = blockIdx.x * 64 + wave * 16 + l16;
    const int ngrp = blockIdx.y * NT * 16;
    const size_t wgrp = (size_t)blockIdx.y * NT * KT * 512;
    const int ktbeg = SPLITK ? blockIdx.z * ktc : 0;
    const int ktend = SPLITK ? ktbeg + ktc : KT;
    float* Cb = SPLITK ? C + (size_t)blockIdx.z * M * N : C;

    if (FUSE_STATS) {
        sstat[tid] = 0.f;
        sstat[tid + 256] = 0.f;
        __syncthreads();
    }

    f32x4 acc[NT] = {};

    for (int kt = ktbeg; kt < ktend; ++kt) {
        const int kq = kt * 32 + quad * 8;
        const float* ap = A + (size_t)mrow * Kst + kq;
        float4 x0 = *(const float4*)ap;
        float4 x1 = *(const float4*)(ap + 4);
        float a8[8] = {x0.x, x0.y, x0.z, x0.w, x1.x, x1.y, x1.z, x1.w};
        if (BNRELU_A) {
            float4 sc0 = *(const float4*)&scsh[kq];
            float4 sc1 = *(const float4*)&scsh[kq + 4];
            float4 sh0 = *(const float4*)&scsh[256 + kq];
            float4 sh1 = *(const float4*)&scsh[256 + kq + 4];
            float sc[8] = {sc0.x, sc0.y, sc0.z, sc0.w, sc1.x, sc1.y, sc1.z, sc1.w};
            float sh[8] = {sh0.x, sh0.y, sh0.z, sh0.w, sh1.x, sh1.y, sh1.z, sh1.w};
#pragma unroll
            for (int i = 0; i < 8; ++i) a8[i] = fmaxf(a8[i] * sc[i] + sh[i], 0.f);
        }
        bf16x8 ahi, alo;
#pragma unroll
        for (int i = 0; i < 8; ++i) {
            short h = f2bf(a8[i]);
            ahi[i] = h;
            alo[i] = f2bf(a8[i] - bf2f(h));
        }
#pragma unroll
        for (int nt = 0; nt < NT; ++nt) {
            const size_t boff = wgrp + (((size_t)nt * KT + kt) << 9) + (lane << 3);
            bf16x8 bh = *(const bf16x8*)(whi + boff);
            bf16x8 bl = *(const bf16x8*)(wlo + boff);
            acc[nt] = __builtin_amdgcn_mfma_f32_16x16x32_bf16(ahi, bh, acc[nt], 0, 0, 0);
            acc[nt] = __builtin_amdgcn_mfma_f32_16x16x32_bf16(alo, bh, acc[nt], 0, 0, 0);
            acc[nt] = __builtin_amdgcn_mfma_f32_16x16x32_bf16(ahi, bl, acc[nt], 0, 0, 0);
            acc[nt] = __builtin_amdgcn_mfma_f32_16x16x32_bf16(alo, bl, acc[nt], 0, 0, 0);
        }
    }

    // Epilogue. C/D frag: col = l16 (+16*nt), row = quad*4 + reg (m89-verified).
    const int mbase = blockIdx.x * 64 + wave * 16 + quad * 4;
#pragma unroll
    for (int nt = 0; nt < NT; ++nt) {
        int gn = ngrp + nt * 16 + l16;
        float bv = bias ? bias[gn] : 0.f;
        float s = 0.f, s2 = 0.f;
#pragma unroll
        for (int r = 0; r < 4; ++r) {
            int gm = mbase + r;
            float v = acc[nt][r] + bv;
            if (RELU_OUT) v = fmaxf(v, 0.f);
            if (gm < M) {
                Cb[(size_t)gm * N + gn] = v;
                if (FUSE_STATS) {
                    s += v;
                    s2 += v * v;
                }
            }
        }
        if (FUSE_STATS) {
            s += __shfl_xor(s, 16);
            s += __shfl_xor(s, 32);
            s2 += __shfl_xor(s2, 16);
            s2 += __shfl_xor(s2, 32);
            if (quad == 0) {
                atomicAdd(&sstat[gn], s);
                atomicAdd(&sstat[256 + gn], s2);
            }
        }
    }
    if (FUSE_STATS) {
        __syncthreads();
        if (tid < N) {
            atomicAdd(&stats[tid], sstat[tid]);
            atomicAdd(&stats[256 + tid], sstat[256 + tid]);
        }
    }
}

// ---- reduce 8 split-K partials + bias -> out (fc1: M=2048,N=128) ----
__global__ __launch_bounds__(256) void splitk_reduce_kernel(const float* __restrict__ part,
                                                            const float* __restrict__ bias,
                                                            float* __restrict__ out) {
    const int i4 = blockIdx.x * 256 + threadIdx.x;
    const int TOT4 = NGRAPHS * 128 / 4;  // 65536
    if (i4 >= TOT4) return;
    const float4* p = (const float4*)part;
    float4 acc = make_float4(0.f, 0.f, 0.f, 0.f);
#pragma unroll
    for (int c = 0; c < 8; ++c) {
        float4 v = p[(size_t)c * TOT4 + i4];
        acc.x += v.x; acc.y += v.y; acc.z += v.z; acc.w += v.w;
    }
    float4 b = ((const float4*)bias)[i4 & 31];
    acc.x += b.x; acc.y += b.y; acc.z += b.z; acc.w += b.w;
    ((float4*)out)[i4] = acc;
}

// ---- segmented pool over sorted batch ----
__global__ __launch_bounds__(128) void pool_seg_kernel(const float* __restrict__ h,
                                                       const int* __restrict__ gstart,
                                                       float* __restrict__ g) {
    int gr = blockIdx.x;
    int t = threadIdx.x;
    int beg = gstart[gr];
    int end = gstart[gr + 1];
    float acc = 0.f;
    for (int r = beg; r < end; ++r) acc += h[(size_t)r * 128 + t];
    g[(size_t)gr * 128 + t] = acc;
}

extern "C" void kernel_launch(void* const* d_in, const int* in_sizes, int n_in, void* d_out,
                              int out_size, void* d_ws, size_t ws_size, hipStream_t stream) {
    const float* x = (const float*)d_in[0];
    const int* ei = (const int*)d_in[1];
    const int* batch = (const int*)d_in[2];
    const int* srcA = ei;
    const int* dstA = ei + NEDGES;

    const float* g0_w1 = (const float*)d_in[3];
    const float* g0_b1 = (const float*)d_in[4];
    const float* g0_ga = (const float*)d_in[5];
    const float* g0_be = (const float*)d_in[6];
    const float* g0_w2 = (const float*)d_in[7];
    const float* g0_b2 = (const float*)d_in[8];
    const float* g1_w1 = (const float*)d_in[9];
    const float* g1_b1 = (const float*)d_in[10];
    const float* g1_ga = (const float*)d_in[11];
    const float* g1_be = (const float*)d_in[12];
    const float* g1_w2 = (const float*)d_in[13];
    const float* g1_b2 = (const float*)d_in[14];
    const float* g2_w1 = (const float*)d_in[15];
    const float* g2_b1 = (const float*)d_in[16];
    const float* g2_ga = (const float*)d_in[17];
    const float* g2_be = (const float*)d_in[18];
    const float* g2_w2 = (const float*)d_in[19];
    const float* g2_b2 = (const float*)d_in[20];
    const float* fc0_w = (const float*)d_in[21];
    const float* fc0_b = (const float*)d_in[22];
    const float* fc1_w = (const float*)d_in[23];
    const float* fc1_b = (const float*)d_in[24];

    // --- workspace layout (~228 MB) ---
    float* ws = (float*)d_ws;
    const size_t BUF = (size_t)NNODES * 256;
    float* R0 = ws;
    float* R1 = R0 + BUF;  // also fc1 split-K partial buffer (8*2048*128 floats)
    float* stats = R1 + BUF;                         // 512
    float* scsh = stats + 512;                       // 512
    float* g = scsh + 512;                           // 2048*128 pooled
    float* gh = g + (size_t)NGRAPHS * 128;           // 2048*1024 fc hidden
    int* deg = (int*)(gh + (size_t)NGRAPHS * 1024);  // NNODES
    int* rowptr = deg + NNODES;                      // NNODES+1
    int* cursor = rowptr + NNODES + 4;               // NNODES
    int* adj = cursor + NNODES;                      // NEDGES
    int* partials = adj + NEDGES;                    // 391
    int* gstart = partials + 512;                    // NGRAPHS+1
    // W-fragment slots: 6 GIN (65536 hi + 65536 lo) + fc0/fc1 (131072 hi + 131072 lo each)
    short* wf = (short*)(gstart + 2052);
    short* whi[8];
    short* wlo[8];
    for (int i = 0; i < 6; ++i) {
        whi[i] = wf + (size_t)i * 131072;
        wlo[i] = whi[i] + 65536;
    }
    whi[6] = wf + 6 * 131072;
    wlo[6] = whi[6] + 131072;
    whi[7] = whi[6] + 262144;
    wlo[7] = whi[7] + 131072;

    const int GB = (NNODES + 63) / 64;    // 1563 mfma-GEMM row-blocks
    const int NB = (NNODES + 255) / 256;  // 391 scan blocks

    // --- build CSR + graph bounds once ---
    hipMemsetAsync(deg, 0, NNODES * sizeof(int), stream);
    hipMemsetAsync(stats, 0, 512 * sizeof(float), stream);  // bnfinal re-zeroes thereafter
    deg_kernel<<<(NEDGES + 255) / 256, 256, 0, stream>>>(dstA, deg);
    scan1_kernel<<<NB, 256, 0, stream>>>(deg, partials);
    scan2_kernel<<<1, 512, 0, stream>>>(partials, NB);
    scan3_kernel<<<NB, 256, 0, stream>>>(deg, partials, rowptr, cursor, batch, gstart);
    fill_kernel<<<(NEDGES + 255) / 256, 256, 0, stream>>>(srcA, dstA, cursor, adj);

    // --- W-fragment pre-passes ---
    wprep_kernel<<<(8 * 3 * 512 + 255) / 256, 256, 0, stream>>>(g0_w1, 66, 128, 3, whi[0], wlo[0]);
    wprep_kernel<<<(8 * 4 * 512 + 255) / 256, 256, 0, stream>>>(g0_w2, 128, 128, 4, whi[1], wlo[1]);
    wprep_kernel<<<(16 * 4 * 512 + 255) / 256, 256, 0, stream>>>(g1_w1, 128, 256, 4, whi[2], wlo[2]);
    wprep_kernel<<<(16 * 8 * 512 + 255) / 256, 256, 0, stream>>>(g1_w2, 256, 256, 8, whi[3], wlo[3]);
    wprep_kernel<<<(8 * 8 * 512 + 255) / 256, 256, 0, stream>>>(g2_w1, 256, 128, 8, whi[4], wlo[4]);
    wprep_kernel<<<(8 * 4 * 512 + 255) / 256, 256, 0, stream>>>(g2_w2, 128, 128, 4, whi[5], wlo[5]);
    wprep_kernel<<<(64 * 4 * 512 + 255) / 256, 256, 0, stream>>>(fc0_w, 128, 1024, 4, whi[6], wlo[6]);
    wprep_kernel<<<(8 * 32 * 512 + 255) / 256, 256, 0, stream>>>(fc1_w, 1024, 128, 32, whi[7], wlo[7]);

    // ================= Layer 0 (66 -> 128 -> 128) =================
    gather_kernel<66, 2, 68><<<(NNODES * 33 + 255) / 256, 256, 0, stream>>>(x, rowptr, adj, R0,
                                                                            nullptr);
    gemm_mfma_kernel<8, false, false, true, false><<<GB, 256, 0, stream>>>(
        R0, whi[0], wlo[0], g0_b1, nullptr, R1, stats, NNODES, 68, 3, 128, 0);
    bnfinal_kernel<<<1, 256, 0, stream>>>(stats, g0_ga, g0_be, scsh, 128, 1.0f / NNODES);
    gemm_mfma_kernel<8, true, true, false, false><<<GB, 256, 0, stream>>>(
        R1, whi[1], wlo[1], g0_b2, scsh, R0, nullptr, NNODES, 128, 4, 128, 0);

    // ================= Layer 1 (128 -> 256 -> 256) =================
    gather_kernel<128, 4, 128><<<(NNODES * 32 + 255) / 256, 256, 0, stream>>>(R0, rowptr, adj, R1,
                                                                              nullptr);
    gemm_mfma_kernel<16, false, false, true, false><<<GB, 256, 0, stream>>>(
        R1, whi[2], wlo[2], g1_b1, nullptr, R0, stats, NNODES, 128, 4, 256, 0);
    bnfinal_kernel<<<1, 256, 0, stream>>>(stats, g1_ga, g1_be, scsh, 256, 1.0f / NNODES);
    gemm_mfma_kernel<16, true, true, false, false><<<GB, 256, 0, stream>>>(
        R0, whi[3], wlo[3], g1_b2, scsh, R1, nullptr, NNODES, 256, 8, 256, 0);

    // ================= Layer 2 (256 -> 128 -> 128), REORDERED =================
    gemm_mfma_kernel<8, false, false, false, false><<<GB, 256, 0, stream>>>(
        R1, whi[4], wlo[4], nullptr, nullptr, R0, nullptr, NNODES, 256, 8, 128, 0);
    gather_kernel<128, 4, 128><<<(NNODES * 32 + 255) / 256, 256, 0, stream>>>(R0, rowptr, adj, R1,
                                                                              g2_b1);
    bnstats_kernel<128><<<128, 256, 0, stream>>>(R1, stats);
    bnfinal_kernel<<<1, 256, 0, stream>>>(stats, g2_ga, g2_be, scsh, 128, 1.0f / NNODES);
    gemm_mfma_kernel<8, true, true, false, false><<<GB, 256, 0, stream>>>(
        R1, whi[5], wlo[5], g2_b2, scsh, R0, nullptr, NNODES, 128, 4, 128, 0);

    // ================= pool + FC head (all MFMA) =================
    pool_seg_kernel<<<NGRAPHS, 128, 0, stream>>>(R0, gstart, g);

    // fc0: relu(g @ fc0_w + fc0_b) -> gh. grid (2048/64, 1024/(8*16)) = (32, 8).
    gemm_mfma_kernel<8, false, true, false, false><<<dim3(NGRAPHS / 64, 8), 256, 0, stream>>>(
        g, whi[6], wlo[6], fc0_b, nullptr, gh, nullptr, NGRAPHS, 128, 4, 1024, 0);
    // fc1 split-K: 8 chunks of KT=4 -> partials in R1 (dead here), then reduce+bias.
    gemm_mfma_kernel<8, false, false, false, true><<<dim3(NGRAPHS / 64, 1, 8), 256, 0, stream>>>(
        gh, whi[7], wlo[7], nullptr, nullptr, R1, nullptr, NGRAPHS, 1024, 32, 128, 4);
    splitk_reduce_kernel<<<(NGRAPHS * 128 / 4 + 255) / 256, 256, 0, stream>>>(R1, fc1_b,
                                                                              (float*)d_out);
}

// Round 15
// 1210.592 us; speedup vs baseline: 1.1864x; 1.0265x over previous
//
#include <hip/hip_runtime.h>

#define NNODES 100000
#define NEDGES 1600000
#define NGRAPHS 2048
#define BN_EPS 1e-5f

typedef __attribute__((ext_vector_type(8))) short bf16x8;
typedef __attribute__((ext_vector_type(4))) float f32x4;

// RNE float -> bf16 (as short bits)
__device__ __forceinline__ short f2bf(float x) {
    unsigned u = __float_as_uint(x);
    unsigned r = u + 0x7FFF + ((u >> 16) & 1);
    return (short)(r >> 16);
}
__device__ __forceinline__ float bf2f(short h) {
    return __uint_as_float(((unsigned)(unsigned short)h) << 16);
}

// ---------------- CSR build ----------------
__global__ __launch_bounds__(256) void deg_kernel(const int* __restrict__ dstA,
                                                  int* __restrict__ deg) {
    int e = blockIdx.x * 256 + threadIdx.x;
    if (e < NEDGES) atomicAdd(&deg[dstA[e]], 1);
}

__global__ __launch_bounds__(256) void scan1_kernel(const int* __restrict__ deg,
                                                    int* __restrict__ partials) {
    int b = blockIdx.x;
    int i = b * 256 + threadIdx.x;
    int v = (i < NNODES) ? deg[i] : 0;
    __shared__ int wsum[4];
#pragma unroll
    for (int off = 32; off; off >>= 1) v += __shfl_down(v, off);
    if ((threadIdx.x & 63) == 0) wsum[threadIdx.x >> 6] = v;
    __syncthreads();
    if (threadIdx.x == 0) partials[b] = wsum[0] + wsum[1] + wsum[2] + wsum[3];
}

__global__ __launch_bounds__(512) void scan2_kernel(int* __restrict__ partials, int nb) {
    __shared__ int s[512];
    int t = threadIdx.x;
    int v = (t < nb) ? partials[t] : 0;
    s[t] = v;
    __syncthreads();
    for (int off = 1; off < 512; off <<= 1) {
        int u = (t >= off) ? s[t - off] : 0;
        __syncthreads();
        s[t] += u;
        __syncthreads();
    }
    if (t < nb) partials[t] = s[t] - v;  // exclusive
}

__global__ __launch_bounds__(256) void scan3_kernel(const int* __restrict__ deg,
                                                    const int* __restrict__ partials,
                                                    int* __restrict__ rowptr,
                                                    int* __restrict__ cursor,
                                                    const int* __restrict__ batch,
                                                    int* __restrict__ gstart) {
    int b = blockIdx.x;
    int t = threadIdx.x;
    int i = b * 256 + t;
    __shared__ int s[256];
    int v = (i < NNODES) ? deg[i] : 0;
    s[t] = v;
    __syncthreads();
    for (int off = 1; off < 256; off <<= 1) {
        int u = (t >= off) ? s[t - off] : 0;
        __syncthreads();
        s[t] += u;
        __syncthreads();
    }
    if (i < NNODES) {
        int ex = partials[b] + s[t] - v;
        rowptr[i] = ex;
        cursor[i] = ex;
        int bb = batch[i];
        int bp = (i == 0) ? -1 : batch[i - 1];
        for (int g = bp + 1; g <= bb; ++g) gstart[g] = i;
        if (i == NNODES - 1)
            for (int g = bb + 1; g <= NGRAPHS; ++g) gstart[g] = NNODES;
    }
    if (b == 0 && t == 0) rowptr[NNODES] = NEDGES;
}

__global__ __launch_bounds__(256) void fill_kernel(const int* __restrict__ srcA,
                                                   const int* __restrict__ dstA,
                                                   int* __restrict__ cursor,
                                                   int* __restrict__ adj) {
    int e = blockIdx.x * 256 + threadIdx.x;
    if (e < NEDGES) {
        int d = dstA[e];
        int loc = atomicAdd(&cursor[d], 1);
        adj[loc] = srcA[e];
    }
}

// ------- gather aggregation: agg[n] = x[n] + sum_{s in adj[n]} x[s] (+bias) -------
// R14 evidence: single-load loop was MLP-bound (3.6 TB/s, VALUBusy 10%). Unroll-by-4
// keeps 4 independent row loads in flight per thread. Stats fusion stays OUT (R13:
// 12500-block global-atomic hotspot serialized the tail).
template <int DIM, int CHUNK, int OSTRIDE>
__global__ __launch_bounds__(256) void gather_kernel(const float* __restrict__ x,
                                                     const int* __restrict__ rowptr,
                                                     const int* __restrict__ adj,
                                                     float* __restrict__ agg,
                                                     const float* __restrict__ bias) {
    constexpr int PE = DIM / CHUNK;
    int gid = blockIdx.x * 256 + threadIdx.x;
    if (gid >= NNODES * PE) return;
    int node = gid / PE;
    int c = gid - node * PE;
    const int beg = rowptr[node];
    const int end = rowptr[node + 1];
    if (CHUNK == 4) {
        const float4* xp = (const float4*)x;
        float4 acc = xp[(size_t)node * PE + c];
        float4 acc1 = make_float4(0.f, 0.f, 0.f, 0.f);
        int i = beg;
        for (; i + 4 <= end; i += 4) {
            int s0 = adj[i + 0];
            int s1 = adj[i + 1];
            int s2 = adj[i + 2];
            int s3 = adj[i + 3];
            float4 v0 = xp[(size_t)s0 * PE + c];
            float4 v1 = xp[(size_t)s1 * PE + c];
            float4 v2 = xp[(size_t)s2 * PE + c];
            float4 v3 = xp[(size_t)s3 * PE + c];
            acc.x += v0.x + v1.x;
            acc.y += v0.y + v1.y;
            acc.z += v0.z + v1.z;
            acc.w += v0.w + v1.w;
            acc1.x += v2.x + v3.x;
            acc1.y += v2.y + v3.y;
            acc1.z += v2.z + v3.z;
            acc1.w += v2.w + v3.w;
        }
        for (; i < end; ++i) {
            int s = adj[i];
            float4 v = xp[(size_t)s * PE + c];
            acc.x += v.x;
            acc.y += v.y;
            acc.z += v.z;
            acc.w += v.w;
        }
        acc.x += acc1.x;
        acc.y += acc1.y;
        acc.z += acc1.z;
        acc.w += acc1.w;
        if (bias) {
            float4 b = *(const float4*)&bias[c * 4];
            acc.x += b.x; acc.y += b.y; acc.z += b.z; acc.w += b.w;
        }
        *(float4*)&agg[(size_t)node * OSTRIDE + c * 4] = acc;
    } else {
        const float2* xp = (const float2*)x;
        float2 acc = xp[(size_t)node * PE + c];
        float2 acc1 = make_float2(0.f, 0.f);
        int i = beg;
        for (; i + 4 <= end; i += 4) {
            int s0 = adj[i + 0];
            int s1 = adj[i + 1];
            int s2 = adj[i + 2];
            int s3 = adj[i + 3];
            float2 v0 = xp[(size_t)s0 * PE + c];
            float2 v1 = xp[(size_t)s1 * PE + c];
            float2 v2 = xp[(size_t)s2 * PE + c];
            float2 v3 = xp[(size_t)s3 * PE + c];
            acc.x += v0.x + v1.x;
            acc.y += v0.y + v1.y;
            acc1.x += v2.x + v3.x;
            acc1.y += v2.y + v3.y;
        }
        for (; i < end; ++i) {
            int s = adj[i];
            float2 v = xp[(size_t)s * PE + c];
            acc.x += v.x;
            acc.y += v.y;
        }
        acc.x += acc1.x;
        acc.y += acc1.y;
        *(float2*)&agg[(size_t)node * OSTRIDE + c * 2] = acc;
    }
}

// ---------------- BN stats (standalone, used once for L2) ----------------
template <int N>
__global__ __launch_bounds__(256) void bnstats_kernel(const float* __restrict__ h,
                                                      float* __restrict__ sums) {
    constexpr int SHIFT = (N == 128) ? 7 : 8;
    int t = blockIdx.x * 256 + threadIdx.x;
    int col = t & (N - 1);
    int slice = t >> SHIFT;
    float s = 0.f, s2 = 0.f;
    for (int r = slice; r < NNODES; r += 256) {
        float v = h[(size_t)r * N + col];
        s += v;
        s2 += v * v;
    }
    atomicAdd(&sums[col], s);
    atomicAdd(&sums[256 + col], s2);
}

// reads sums (sum@c, sumsq@256+c), writes scale@c / shift@256+c, then re-zeroes sums.
__global__ void bnfinal_kernel(float* __restrict__ sums, const float* __restrict__ gamma,
                               const float* __restrict__ beta, float* __restrict__ scsh, int N,
                               float invM) {
    int c = threadIdx.x;  // 256 threads always
    if (c < N) {
        float mean = sums[c] * invM;
        float var = sums[256 + c] * invM - mean * mean;
        float sc = gamma[c] * rsqrtf(var + BN_EPS);
        scsh[c] = sc;
        scsh[256 + c] = beta[c] - mean * sc;
    }
    sums[c] = 0.f;
    sums[256 + c] = 0.f;
}

// ---- W pre-pass: decompose W (Kw x N fp32) into hi/lo bf16 B-fragments ----
// B-frag layout (mfma_f32_16x16x32_bf16): lane holds n=lane&15, k=(lane>>4)*8+j.
// Buffer index: ((nt*KT + kt)*64 + lane)*8 + j.
__global__ __launch_bounds__(256) void wprep_kernel(const float* __restrict__ W, int Kw, int N,
                                                    int KT, short* __restrict__ whi,
                                                    short* __restrict__ wlo) {
    int idx = blockIdx.x * 256 + threadIdx.x;
    int total = (N >> 4) * KT * 512;
    if (idx >= total) return;
    int j = idx & 7;
    int lane = (idx >> 3) & 63;
    int t = idx >> 9;  // nt*KT + kt
    int kt = t % KT;
    int nt = t / KT;
    int k = kt * 32 + ((lane >> 4) << 3) + j;
    int n = (nt << 4) + (lane & 15);
    float w = (k < Kw) ? W[(size_t)k * N + n] : 0.f;
    short hi = f2bf(w);
    short lo = f2bf(w - bf2f(hi));
    whi[idx] = hi;
    wlo[idx] = lo;
}

// ---------------- split-bf16 MFMA GEMM: C = op(A) @ W + bias ----------------
// LDS-free. Block = 4 waves; BM=64 (16 rows/wave); NT N-tiles per block.
// blockIdx.y = N-group. SPLITK: blockIdx.z picks a KT-chunk of size ktc, C offset z*M*N.
template <int NT, bool BNRELU_A, bool RELU_OUT, bool FUSE_STATS, bool SPLITK>
__global__ __launch_bounds__(256) void gemm_mfma_kernel(
    const float* __restrict__ A, const short* __restrict__ whi, const short* __restrict__ wlo,
    const float* __restrict__ bias, const float* __restrict__ scsh, float* __restrict__ C,
    float* __restrict__ stats, int M, int Kst, int KT, int N, int ktc) {
    __shared__ float sstat[512];
    const int tid = threadIdx.x;
    const int wave = tid >> 6;
    const int lane = tid & 63;
    const int quad = lane >> 4;
    const int l16 = lane & 15;
    const int mrow = blockIdx.x * 64 + wave * 16 + l16;
    const int ngrp = blockIdx.y * NT * 16;
    const size_t wgrp = (size_t)blockIdx.y * NT * KT * 512;
    const int ktbeg = SPLITK ? blockIdx.z * ktc : 0;
    const int ktend = SPLITK ? ktbeg + ktc : KT;
    float* Cb = SPLITK ? C + (size_t)blockIdx.z * M * N : C;

    if (FUSE_STATS) {
        sstat[tid] = 0.f;
        sstat[tid + 256] = 0.f;
        __syncthreads();
    }

    f32x4 acc[NT] = {};

    for (int kt = ktbeg; kt < ktend; ++kt) {
        const int kq = kt * 32 + quad * 8;
        const float* ap = A + (size_t)mrow * Kst + kq;
        float4 x0 = *(const float4*)ap;
        float4 x1 = *(const float4*)(ap + 4);
        float a8[8] = {x0.x, x0.y, x0.z, x0.w, x1.x, x1.y, x1.z, x1.w};
        if (BNRELU_A) {
            float4 sc0 = *(const float4*)&scsh[kq];
            float4 sc1 = *(const float4*)&scsh[kq + 4];
            float4 sh0 = *(const float4*)&scsh[256 + kq];
            float4 sh1 = *(const float4*)&scsh[256 + kq + 4];
            float sc[8] = {sc0.x, sc0.y, sc0.z, sc0.w, sc1.x, sc1.y, sc1.z, sc1.w};
            float sh[8] = {sh0.x, sh0.y, sh0.z, sh0.w, sh1.x, sh1.y, sh1.z, sh1.w};
#pragma unroll
            for (int i = 0; i < 8; ++i) a8[i] = fmaxf(a8[i] * sc[i] + sh[i], 0.f);
        }
        bf16x8 ahi, alo;
#pragma unroll
        for (int i = 0; i < 8; ++i) {
            short h = f2bf(a8[i]);
            ahi[i] = h;
            alo[i] = f2bf(a8[i] - bf2f(h));
        }
#pragma unroll
        for (int nt = 0; nt < NT; ++nt) {
            const size_t boff = wgrp + (((size_t)nt * KT + kt) << 9) + (lane << 3);
            bf16x8 bh = *(const bf16x8*)(whi + boff);
            bf16x8 bl = *(const bf16x8*)(wlo + boff);
            acc[nt] = __builtin_amdgcn_mfma_f32_16x16x32_bf16(ahi, bh, acc[nt], 0, 0, 0);
            acc[nt] = __builtin_amdgcn_mfma_f32_16x16x32_bf16(alo, bh, acc[nt], 0, 0, 0);
            acc[nt] = __builtin_amdgcn_mfma_f32_16x16x32_bf16(ahi, bl, acc[nt], 0, 0, 0);
            acc[nt] = __builtin_amdgcn_mfma_f32_16x16x32_bf16(alo, bl, acc[nt], 0, 0, 0);
        }
    }

    // Epilogue. C/D frag: col = l16 (+16*nt), row = quad*4 + reg (m89-verified).
    const int mbase = blockIdx.x * 64 + wave * 16 + quad * 4;
#pragma unroll
    for (int nt = 0; nt < NT; ++nt) {
        int gn = ngrp + nt * 16 + l16;
        float bv = bias ? bias[gn] : 0.f;
        float s = 0.f, s2 = 0.f;
#pragma unroll
        for (int r = 0; r < 4; ++r) {
            int gm = mbase + r;
            float v = acc[nt][r] + bv;
            if (RELU_OUT) v = fmaxf(v, 0.f);
            if (gm < M) {
                Cb[(size_t)gm * N + gn] = v;
                if (FUSE_STATS) {
                    s += v;
                    s2 += v * v;
                }
            }
        }
        if (FUSE_STATS) {
            s += __shfl_xor(s, 16);
            s += __shfl_xor(s, 32);
            s2 += __shfl_xor(s2, 16);
            s2 += __shfl_xor(s2, 32);
            if (quad == 0) {
                atomicAdd(&sstat[gn], s);
                atomicAdd(&sstat[256 + gn], s2);
            }
        }
    }
    if (FUSE_STATS) {
        __syncthreads();
        if (tid < N) {
            atomicAdd(&stats[tid], sstat[tid]);
            atomicAdd(&stats[256 + tid], sstat[256 + tid]);
        }
    }
}

// ---- reduce 8 split-K partials + bias -> out (fc1: M=2048,N=128) ----
__global__ __launch_bounds__(256) void splitk_reduce_kernel(const float* __restrict__ part,
                                                            const float* __restrict__ bias,
                                                            float* __restrict__ out) {
    const int i4 = blockIdx.x * 256 + threadIdx.x;
    const int TOT4 = NGRAPHS * 128 / 4;  // 65536
    if (i4 >= TOT4) return;
    const float4* p = (const float4*)part;
    float4 acc = make_float4(0.f, 0.f, 0.f, 0.f);
#pragma unroll
    for (int c = 0; c < 8; ++c) {
        float4 v = p[(size_t)c * TOT4 + i4];
        acc.x += v.x; acc.y += v.y; acc.z += v.z; acc.w += v.w;
    }
    float4 b = ((const float4*)bias)[i4 & 31];
    acc.x += b.x; acc.y += b.y; acc.z += b.z; acc.w += b.w;
    ((float4*)out)[i4] = acc;
}

// ---- segmented pool over sorted batch ----
__global__ __launch_bounds__(128) void pool_seg_kernel(const float* __restrict__ h,
                                                       const int* __restrict__ gstart,
                                                       float* __restrict__ g) {
    int gr = blockIdx.x;
    int t = threadIdx.x;
    int beg = gstart[gr];
    int end = gstart[gr + 1];
    float acc = 0.f;
    for (int r = beg; r < end; ++r) acc += h[(size_t)r * 128 + t];
    g[(size_t)gr * 128 + t] = acc;
}

extern "C" void kernel_launch(void* const* d_in, const int* in_sizes, int n_in, void* d_out,
                              int out_size, void* d_ws, size_t ws_size, hipStream_t stream) {
    const float* x = (const float*)d_in[0];
    const int* ei = (const int*)d_in[1];
    const int* batch = (const int*)d_in[2];
    const int* srcA = ei;
    const int* dstA = ei + NEDGES;

    const float* g0_w1 = (const float*)d_in[3];
    const float* g0_b1 = (const float*)d_in[4];
    const float* g0_ga = (const float*)d_in[5];
    const float* g0_be = (const float*)d_in[6];
    const float* g0_w2 = (const float*)d_in[7];
    const float* g0_b2 = (const float*)d_in[8];
    const float* g1_w1 = (const float*)d_in[9];
    const float* g1_b1 = (const float*)d_in[10];
    const float* g1_ga = (const float*)d_in[11];
    const float* g1_be = (const float*)d_in[12];
    const float* g1_w2 = (const float*)d_in[13];
    const float* g1_b2 = (const float*)d_in[14];
    const float* g2_w1 = (const float*)d_in[15];
    const float* g2_b1 = (const float*)d_in[16];
    const float* g2_ga = (const float*)d_in[17];
    const float* g2_be = (const float*)d_in[18];
    const float* g2_w2 = (const float*)d_in[19];
    const float* g2_b2 = (const float*)d_in[20];
    const float* fc0_w = (const float*)d_in[21];
    const float* fc0_b = (const float*)d_in[22];
    const float* fc1_w = (const float*)d_in[23];
    const float* fc1_b = (const float*)d_in[24];

    // --- workspace layout (~228 MB) ---
    float* ws = (float*)d_ws;
    const size_t BUF = (size_t)NNODES * 256;
    float* R0 = ws;
    float* R1 = R0 + BUF;  // also fc1 split-K partial buffer (8*2048*128 floats)
    float* stats = R1 + BUF;                         // 512
    float* scsh = stats + 512;                       // 512
    float* g = scsh + 512;                           // 2048*128 pooled
    float* gh = g + (size_t)NGRAPHS * 128;           // 2048*1024 fc hidden
    int* deg = (int*)(gh + (size_t)NGRAPHS * 1024);  // NNODES
    int* rowptr = deg + NNODES;                      // NNODES+1
    int* cursor = rowptr + NNODES + 4;               // NNODES
    int* adj = cursor + NNODES;                      // NEDGES
    int* partials = adj + NEDGES;                    // 391
    int* gstart = partials + 512;                    // NGRAPHS+1
    // W-fragment slots: 6 GIN (65536 hi + 65536 lo) + fc0/fc1 (131072 hi + 131072 lo each)
    short* wf = (short*)(gstart + 2052);
    short* whi[8];
    short* wlo[8];
    for (int i = 0; i < 6; ++i) {
        whi[i] = wf + (size_t)i * 131072;
        wlo[i] = whi[i] + 65536;
    }
    whi[6] = wf + 6 * 131072;
    wlo[6] = whi[6] + 131072;
    whi[7] = whi[6] + 262144;
    wlo[7] = whi[7] + 131072;

    const int GB = (NNODES + 63) / 64;    // 1563 mfma-GEMM row-blocks
    const int NB = (NNODES + 255) / 256;  // 391 scan blocks

    // --- build CSR + graph bounds once ---
    hipMemsetAsync(deg, 0, NNODES * sizeof(int), stream);
    hipMemsetAsync(stats, 0, 512 * sizeof(float), stream);  // bnfinal re-zeroes thereafter
    deg_kernel<<<(NEDGES + 255) / 256, 256, 0, stream>>>(dstA, deg);
    scan1_kernel<<<NB, 256, 0, stream>>>(deg, partials);
    scan2_kernel<<<1, 512, 0, stream>>>(partials, NB);
    scan3_kernel<<<NB, 256, 0, stream>>>(deg, partials, rowptr, cursor, batch, gstart);
    fill_kernel<<<(NEDGES + 255) / 256, 256, 0, stream>>>(srcA, dstA, cursor, adj);

    // --- W-fragment pre-passes ---
    wprep_kernel<<<(8 * 3 * 512 + 255) / 256, 256, 0, stream>>>(g0_w1, 66, 128, 3, whi[0], wlo[0]);
    wprep_kernel<<<(8 * 4 * 512 + 255) / 256, 256, 0, stream>>>(g0_w2, 128, 128, 4, whi[1], wlo[1]);
    wprep_kernel<<<(16 * 4 * 512 + 255) / 256, 256, 0, stream>>>(g1_w1, 128, 256, 4, whi[2], wlo[2]);
    wprep_kernel<<<(16 * 8 * 512 + 255) / 256, 256, 0, stream>>>(g1_w2, 256, 256, 8, whi[3], wlo[3]);
    wprep_kernel<<<(8 * 8 * 512 + 255) / 256, 256, 0, stream>>>(g2_w1, 256, 128, 8, whi[4], wlo[4]);
    wprep_kernel<<<(8 * 4 * 512 + 255) / 256, 256, 0, stream>>>(g2_w2, 128, 128, 4, whi[5], wlo[5]);
    wprep_kernel<<<(64 * 4 * 512 + 255) / 256, 256, 0, stream>>>(fc0_w, 128, 1024, 4, whi[6], wlo[6]);
    wprep_kernel<<<(8 * 32 * 512 + 255) / 256, 256, 0, stream>>>(fc1_w, 1024, 128, 32, whi[7], wlo[7]);

    // ================= Layer 0 (66 -> 128 -> 128) =================
    gather_kernel<66, 2, 68><<<(NNODES * 33 + 255) / 256, 256, 0, stream>>>(x, rowptr, adj, R0,
                                                                            nullptr);
    gemm_mfma_kernel<8, false, false, true, false><<<GB, 256, 0, stream>>>(
        R0, whi[0], wlo[0], g0_b1, nullptr, R1, stats, NNODES, 68, 3, 128, 0);
    bnfinal_kernel<<<1, 256, 0, stream>>>(stats, g0_ga, g0_be, scsh, 128, 1.0f / NNODES);
    gemm_mfma_kernel<8, true, true, false, false><<<GB, 256, 0, stream>>>(
        R1, whi[1], wlo[1], g0_b2, scsh, R0, nullptr, NNODES, 128, 4, 128, 0);

    // ================= Layer 1 (128 -> 256 -> 256) =================
    gather_kernel<128, 4, 128><<<(NNODES * 32 + 255) / 256, 256, 0, stream>>>(R0, rowptr, adj, R1,
                                                                              nullptr);
    gemm_mfma_kernel<16, false, false, true, false><<<GB, 256, 0, stream>>>(
        R1, whi[2], wlo[2], g1_b1, nullptr, R0, stats, NNODES, 128, 4, 256, 0);
    bnfinal_kernel<<<1, 256, 0, stream>>>(stats, g1_ga, g1_be, scsh, 256, 1.0f / NNODES);
    gemm_mfma_kernel<16, true, true, false, false><<<GB, 256, 0, stream>>>(
        R0, whi[3], wlo[3], g1_b2, scsh, R1, nullptr, NNODES, 256, 8, 256, 0);

    // ================= Layer 2 (256 -> 128 -> 128), REORDERED =================
    gemm_mfma_kernel<8, false, false, false, false><<<GB, 256, 0, stream>>>(
        R1, whi[4], wlo[4], nullptr, nullptr, R0, nullptr, NNODES, 256, 8, 128, 0);
    gather_kernel<128, 4, 128><<<(NNODES * 32 + 255) / 256, 256, 0, stream>>>(R0, rowptr, adj, R1,
                                                                              g2_b1);
    bnstats_kernel<128><<<128, 256, 0, stream>>>(R1, stats);
    bnfinal_kernel<<<1, 256, 0, stream>>>(stats, g2_ga, g2_be, scsh, 128, 1.0f / NNODES);
    gemm_mfma_kernel<8, true, true, false, false><<<GB, 256, 0, stream>>>(
        R1, whi[5], wlo[5], g2_b2, scsh, R0, nullptr, NNODES, 128, 4, 128, 0);

    // ================= pool + FC head (all MFMA) =================
    pool_seg_kernel<<<NGRAPHS, 128, 0, stream>>>(R0, gstart, g);

    // fc0: relu(g @ fc0_w + fc0_b) -> gh. grid (2048/64, 1024/(8*16)) = (32, 8).
    gemm_mfma_kernel<8, false, true, false, false><<<dim3(NGRAPHS / 64, 8), 256, 0, stream>>>(
        g, whi[6], wlo[6], fc0_b, nullptr, gh, nullptr, NGRAPHS, 128, 4, 1024, 0);
    // fc1 split-K: 8 chunks of KT=4 -> partials in R1 (dead here), then reduce+bias.
    gemm_mfma_kernel<8, false, false, false, true><<<dim3(NGRAPHS / 64, 1, 8), 256, 0, stream>>>(
        gh, whi[7], wlo[7], nullptr, nullptr, R1, nullptr, NGRAPHS, 1024, 32, 128, 4);
    splitk_reduce_kernel<<<(NGRAPHS * 128 / 4 + 255) / 256, 256, 0, stream>>>(R1, fc1_b,
                                                                              (float*)d_out);
}